// Round 5
// baseline (1128.338 us; speedup 1.0000x reference)
//
#include <hip/hip_runtime.h>
#include <hip/hip_bf16.h>

#define BATCH 4096
#define TSTEPS 80
#define VOCAB 10000
#define EDIM 100
#define UDIM 1024

// LDS: B weights 4 j x 36 s x 64 lanes x 16 B = 147456 B
//      + 16 waves x 320-half epilogue scratch = 10240 B -> 157696 B static
#define B_HALFS 73728

// s_getreg imm: hwreg(HW_REG_XCC_ID=20, offset=0, size=32) = 20 | (31<<11)
#define HWREG_XCC_ID 63508

typedef _Float16 half8 __attribute__((ext_vector_type(8)));
typedef _Float16 half4 __attribute__((ext_vector_type(4)));
typedef float float4v __attribute__((ext_vector_type(4)));

// Frag-major layout: chunk(blk, kblk, lane) = 16 B holding
// row = blk*16 + (lane&15), k = kblk*32 + (lane>>4)*8 .. +8.
// h:  [mblk 256][kblk 32][lane]   Wf: [nblk 64][kblk 32][lane]
// xe: [t][mblk 256][kblk 4][lane] Wxf:[nblk 64][kblk 4][lane]

__device__ __forceinline__ void load_lds16(const void* g, void* l) {
    __builtin_amdgcn_global_load_lds(
        (const __attribute__((address_space(1))) unsigned int*)g,
        (__attribute__((address_space(3))) unsigned int*)l,
        16, 0, 0);
}

__device__ __forceinline__ float tanh_fast(float x) {
    return 1.0f - 2.0f / (__expf(2.0f * x) + 1.0f);
}

__global__ __launch_bounds__(256) void convert_wh_frag(const float* __restrict__ Wh,
                                                       _Float16* __restrict__ Wf) {
    int cid = blockIdx.x * 256 + threadIdx.x;
    int lane = cid & 63, kblk = (cid >> 6) & 31, nblk = cid >> 11;
    int n = nblk * 16 + (lane & 15);
    int kb = kblk * 32 + (lane >> 4) * 8;
    half8 v;
    #pragma unroll
    for (int e = 0; e < 8; ++e) v[e] = (_Float16)Wh[(kb + e) * UDIM + n];
    *((half8*)Wf + cid) = v;
}

__global__ __launch_bounds__(256) void convert_wx_frag(const float* __restrict__ Wx,
                                                       _Float16* __restrict__ Wxf) {
    int cid = blockIdx.x * 256 + threadIdx.x;
    int lane = cid & 63, kblk = (cid >> 6) & 3, nblk = cid >> 8;
    int n = nblk * 16 + (lane & 15);
    int kb = kblk * 32 + (lane >> 4) * 8;
    half8 v;
    #pragma unroll
    for (int e = 0; e < 8; ++e)
        v[e] = (kb + e < EDIM) ? (_Float16)Wx[(kb + e) * UDIM + n] : (_Float16)0.0f;
    *((half8*)Wxf + cid) = v;
}

// 2 independent token->emb chains per thread (gather-latency-bound kernel)
__global__ __launch_bounds__(256) void embed_gather_frag(
        const int* __restrict__ inputs, const float* __restrict__ emb,
        _Float16* __restrict__ xe) {
    const int c = blockIdx.x * 256 + threadIdx.x;
    int cid[2] = { c, c + 2621440 };
    const float* src[2];
    int kb[2];
    #pragma unroll
    for (int u = 0; u < 2; ++u) {
        int lane = cid[u] & 63, kblk = (cid[u] >> 6) & 3;
        int mblk = (cid[u] >> 8) & 255, t = cid[u] >> 16;
        int m = mblk * 16 + (lane & 15);
        kb[u] = kblk * 32 + (lane >> 4) * 8;
        int tok = inputs[m * TSTEPS + t];
        src[u] = emb + (size_t)tok * EDIM;
    }
    #pragma unroll
    for (int u = 0; u < 2; ++u) {
        half8 v;
        #pragma unroll
        for (int e = 0; e < 8; ++e)
            v[e] = (kb[u] + e < EDIM) ? (_Float16)src[u][kb[u] + e] : (_Float16)0.0f;
        *((half8*)xe + cid[u]) = v;
    }
}

// Persistent kernel, 256 blocks x 1024 threads (16 waves = 4/SIMD; 157.7 KB
// LDS keeps 1 block/CU). Tile 256(M) x 64(N).
// NEW (this round): every pipe is <20% busy per SIMD and 4 structural
// experiments bounded barrier/LDS/burst effects at <2% each -> the kernel is
// LATENCY-bound at 2 waves/SIMD (Occupancy 22%). Fix: DOUBLE wave-level
// parallelism at constant LDS. 16 waves split M x j: wave=(wg,wj); wg owns
// 32 M-rows (mblk pair), wj owns j-half {2wj, 2wj+1}. Per-wave work halves;
// per-CU LDS B traffic unchanged (j-split); A-reads double (L2 has 4x
// headroom). R4's rotated visit order + own-chunk registers kept -- with
// j-split each wave's epilogue output IS exactly its own k-chunk
// (kblk = 2nt + wj). Epilogue scratch reworked to 320 halfs/wave (two
// jl-passes, b64 reads, conflict-free 20-half stride) so 16 waves fit the
// same 157696 B LDS. B-prefetch deepened to dist-4 (4-MFMA groups have
// half the LDS-latency cover of the old 8-MFMA groups).
__global__ __launch_bounds__(1024, 4) void rnn_persist(
        _Float16* __restrict__ hA, _Float16* __restrict__ hB,
        const _Float16* __restrict__ xe,
        const _Float16* __restrict__ Wf, const _Float16* __restrict__ Wxf,
        const float* __restrict__ bias,
        unsigned* vote, unsigned* barg, unsigned* bar, unsigned* fbar)
{
    __shared__ __align__(16) _Float16 smem[B_HALFS + 16 * 320];  // 157696 B
    __shared__ unsigned sFast;

    const int tid  = threadIdx.x;
    const int lane = tid & 63, wave = tid >> 6;
    const int wg = wave >> 1, wj = wave & 1;
    const int bid  = blockIdx.x;
    const int mt = bid & 15, nt = bid >> 4;
    const int lrow = lane & 15, lq = lane >> 4;

    // ---- XCD-locality vote + one global barrier (atomics only) ----
    if (tid == 0) {
        unsigned xcd = ((unsigned)__builtin_amdgcn_s_getreg(HWREG_XCC_ID)) & 7u;
        __hip_atomic_fetch_or(&vote[mt], 1u << xcd, __ATOMIC_RELAXED,
                              __HIP_MEMORY_SCOPE_AGENT);
        __builtin_amdgcn_s_waitcnt(0);
        __hip_atomic_fetch_add(barg, 1u, __ATOMIC_RELAXED, __HIP_MEMORY_SCOPE_AGENT);
        while (__hip_atomic_load(barg, __ATOMIC_RELAXED,
                                 __HIP_MEMORY_SCOPE_AGENT) < 256u)
            __builtin_amdgcn_s_sleep(1);
        unsigned allv = 0u, own = 0u;
        for (int g = 0; g < 16; ++g) {
            unsigned v = __hip_atomic_load(&vote[g], __ATOMIC_RELAXED,
                                           __HIP_MEMORY_SCOPE_AGENT);
            allv |= v;
            if (g == mt) own = v;
        }
        const bool single = own != 0u && (own & (own - 1u)) == 0u;
        sFast = (single && __popc(allv) == 8) ? 1u : 0u;
    }
    __syncthreads();
    const bool fast = sFast != 0u;

    // ---- Load B slice into LDS once: [j(4)][s(36)][lane][8]; waves 0-3 ----
    if (wave < 4) {
        const half8* wx8 = (const half8*)Wxf;
        const half8* wh8 = (const half8*)Wf;
        #pragma unroll 1
        for (int s = 0; s < 36; ++s) {
            const half8* src = (s < 4)
                ? wx8 + ((size_t)(nt * 4 + wave) * 4 + s) * 64 + lane
                : wh8 + ((size_t)(nt * 4 + wave) * 32 + (s - 4)) * 64 + lane;
            load_lds16(src, smem + ((wave * 36 + s) * 64 + lane) * 8);
        }
    }
    __syncthreads();

    _Float16* tb = smem + B_HALFS + wave * 320;   // epilogue scratch, wave-private

    float bj[2];
    #pragma unroll
    for (int jl = 0; jl < 2; ++jl)
        bj[jl] = bias[nt * 64 + (wj * 2 + jl) * 16 + lrow];

    int mblk[2];                                  // wave tile: 32 M rows
    #pragma unroll
    for (int i = 0; i < 2; ++i) mblk[i] = mt * 16 + wg * 2 + i;

    unsigned* mybar = bar + mt * 32;              // fallback single counter
    unsigned* mycnt = fbar + (mt * 16 + nt) * 4;  // own producer counter (16 B stride)

    const int cbw = nt * 2 + wj;                  // rotated base = OWN chunk

// load B slice s (absolute slice index), j-half wj -> bf[2]
#define LDB(bf, s) { _Pragma("unroll") \
    for (int jl = 0; jl < 2; ++jl) \
        bf[jl] = *(const half8*)&smem[(((wj * 2 + jl) * 36 + (s)) * 64 + lane) * 8]; }
// load B for rotated h-visit v
#define LDBR(bf, v) { const int s_ = 4 + ((cbw + (v)) & 31); LDB(bf, s_) }
#define FMAB(A, B) { _Pragma("unroll") \
    for (int i = 0; i < 2; ++i) { _Pragma("unroll") \
        for (int jl = 0; jl < 2; ++jl) \
            acc[i][jl] = __builtin_amdgcn_mfma_f32_16x16x32_f16(A[i], B[jl], acc[i][jl], 0, 0, 0); } }
#define LDHR(A, v) { const int c_ = (cbw + (v)) & 31; _Pragma("unroll") \
    for (int i = 0; i < 2; ++i) A[i] = pah[i][c_ * 64]; }
#define ZACC { _Pragma("unroll") \
    for (int i = 0; i < 2; ++i) { _Pragma("unroll") \
        for (int jl = 0; jl < 2; ++jl) { acc[i][jl][0]=0.f; acc[i][jl][1]=0.f; acc[i][jl][2]=0.f; acc[i][jl][3]=0.f; } } }

    float4v acc[2][2];
    half8 a0[2], a1[2], a2[2], a3[2];
    half8 b0[2], b1[2], b2[2], b3[2];
    half8 own[2];                                 // own chunk (kblk=2nt+wj); h(0)=0
    #pragma unroll
    for (int e = 0; e < 8; ++e) { own[0][e] = (_Float16)0.0f; own[1][e] = (_Float16)0.0f; }

    // x-segment for a step: acc += xe_tn @ Wx  (B slices 0..3, j-half wj)
    auto xfma = [&](int tn) {
        const half8* xe8 = (const half8*)xe + (size_t)tn * 65536;
        #pragma unroll
        for (int i = 0; i < 2; ++i) {
            const half8* px = xe8 + (size_t)mblk[i] * 4 * 64 + lane;
            a0[i] = px[0]; a1[i] = px[64]; a2[i] = px[128]; a3[i] = px[192];
        }
        LDB(b0, 0); LDB(b1, 1); LDB(b2, 2); LDB(b3, 3);
        FMAB(a0, b0);
        FMAB(a1, b1);
        FMAB(a2, b2);
        FMAB(a3, b3);
    };

    ZACC;
    xfma(0);

    #pragma unroll 1
    for (int t = 0; t < TSTEPS; ++t) {
        const _Float16* hi = (t & 1) ? hB : hA;
        _Float16*       ho = (t & 1) ? hA : hB;

        const half8* pah[2];
        #pragma unroll
        for (int i = 0; i < 2; ++i)
            pah[i] = (const half8*)hi + (size_t)mblk[i] * 32 * 64 + lane;

        // ---- h-loop: 32 visits, rotated order chunk=(2nt+wj+v)&31.
        //      Visit 0 = own chunk from registers. A dist-4, B dist-4.
        #pragma unroll
        for (int i = 0; i < 2; ++i) a0[i] = own[i];
        LDHR(a1, 1); LDHR(a2, 2); LDHR(a3, 3);
        LDBR(b0, 0); LDBR(b1, 1); LDBR(b2, 2); LDBR(b3, 3);
        #pragma unroll 1
        for (int v = 0; v < 28; v += 4) {
            FMAB(a0, b0); LDBR(b0, v + 4); LDHR(a0, v + 4);
            FMAB(a1, b1); LDBR(b1, v + 5); LDHR(a1, v + 5);
            FMAB(a2, b2); LDBR(b2, v + 6); LDHR(a2, v + 6);
            FMAB(a3, b3); LDBR(b3, v + 7); LDHR(a3, v + 7);
        }
        // tail: visits 28..31 (operands loaded at v=24)
        FMAB(a0, b0);
        FMAB(a1, b1);
        FMAB(a2, b2);
        FMAB(a3, b3);

        // ---- Epilogue: tanh + C->A layout, 2 jl-passes through 320-half
        //      scratch (16 rows x 20-half stride; b64 reads, conflict-free).
        //      Consumer lane (lrow,lq) needs k = lq*8..+8 of chunk 2nt+wj:
        //      jl-half = lq>>1, in-half col = (lq&1)*8.
        #pragma unroll
        for (int i = 0; i < 2; ++i) {
            half4 p0a, p0b, p1a, p1b;
            #pragma unroll
            for (int r = 0; r < 4; ++r)
                tb[(lq * 4 + r) * 20 + lrow] =
                    (_Float16)tanh_fast(acc[i][0][r] + bj[0]);
            p0a = *(const half4*)&tb[lrow * 20 + (lq & 1) * 8];
            p0b = *(const half4*)&tb[lrow * 20 + (lq & 1) * 8 + 4];
            #pragma unroll
            for (int r = 0; r < 4; ++r)
                tb[(lq * 4 + r) * 20 + lrow] =
                    (_Float16)tanh_fast(acc[i][1][r] + bj[1]);
            p1a = *(const half4*)&tb[lrow * 20 + (lq & 1) * 8];
            p1b = *(const half4*)&tb[lrow * 20 + (lq & 1) * 8 + 4];
            half4 sa = (lq < 2) ? p0a : p1a;
            half4 sb = (lq < 2) ? p0b : p1b;
            half8 v;
            #pragma unroll
            for (int e = 0; e < 4; ++e) { v[e] = sa[e]; v[e + 4] = sb[e]; }
            own[i] = v;
            *((half8*)ho + (size_t)(mblk[i] * 32 + cbw) * 64 + lane) = v;
        }

        // ---- x-segment of step t+1 (independent of h_{t+1}) BEFORE barrier ----
        if (t < TSTEPS - 1) {
            ZACC;
            xfma(t + 1);
            __syncthreads();    // drains all waves' h stores to L2
            if (fast) {
                // distributed barrier: parallel RMWs + 16-lane parallel spin
                if (tid == 0)
                    __hip_atomic_fetch_add(mycnt, 1u, __ATOMIC_RELAXED,
                                           __HIP_MEMORY_SCOPE_AGENT);
                if (tid < 16) {
                    while (__hip_atomic_load(&fbar[(mt * 16 + tid) * 4],
                                             __ATOMIC_RELAXED,
                                             __HIP_MEMORY_SCOPE_AGENT)
                           < (unsigned)(t + 1))
                        __builtin_amdgcn_s_sleep(1);
                }
            } else if (tid == 0) {
                __builtin_amdgcn_fence(__ATOMIC_RELEASE, "agent");
                __hip_atomic_fetch_add(mybar, 1u, __ATOMIC_RELAXED,
                                       __HIP_MEMORY_SCOPE_AGENT);
                const unsigned target = 16u * (unsigned)(t + 1);
                while (__hip_atomic_load(mybar, __ATOMIC_RELAXED,
                                         __HIP_MEMORY_SCOPE_AGENT) < target)
                    __builtin_amdgcn_s_sleep(1);
                __builtin_amdgcn_fence(__ATOMIC_ACQUIRE, "agent");
            }
            __syncthreads();
        }
    }
#undef LDB
#undef LDBR
#undef FMAB
#undef LDHR
#undef ZACC
}

// out[b] = h[b,:].Wo + bo, h frag-major
__global__ __launch_bounds__(256) void out_proj(const _Float16* __restrict__ h,
                                                const float* __restrict__ Wo,
                                                const float* __restrict__ bo,
                                                float* __restrict__ out) {
    const int lane = threadIdx.x & 63;
    const int wave = threadIdx.x >> 6;
    const int row = blockIdx.x * 4 + wave;
    const int mblk = row >> 4, lb = row & 15;
    const half8* hf = (const half8*)h;
    float s = 0.0f;
    #pragma unroll
    for (int c = 0; c < 2; ++c) {
        const int kblk = lane >> 1;
        const int q = (lane & 1) * 2 + c;
        half8 v = hf[(size_t)(mblk * 32 + kblk) * 64 + lb + q * 16];
        const int k0 = kblk * 32 + q * 8;
        #pragma unroll
        for (int e = 0; e < 8; ++e) s += (float)v[e] * Wo[k0 + e];
    }
    #pragma unroll
    for (int off = 32; off > 0; off >>= 1) s += __shfl_down(s, off, 64);
    if (lane == 0) out[row] = s + bo[0];
}

extern "C" void kernel_launch(void* const* d_in, const int* in_sizes, int n_in,
                              void* d_out, int out_size, void* d_ws, size_t ws_size,
                              hipStream_t stream) {
    const int*   inputs = (const int*)  d_in[0];
    const float* emb    = (const float*)d_in[1];
    const float* Wx     = (const float*)d_in[2];
    const float* Wh     = (const float*)d_in[3];
    const float* b      = (const float*)d_in[4];
    const float* Wo     = (const float*)d_in[5];
    const float* bo     = (const float*)d_in[6];
    float* out = (float*)d_out;

    char* ws = (char*)d_ws;
    _Float16* Wf   = (_Float16*)ws;                          // 2 MB
    _Float16* Wxf  = (_Float16*)(ws + (2u  << 20));          // 256 KB
    _Float16* hA   = (_Float16*)(ws + (3u  << 20));          // 8 MB
    _Float16* hB   = (_Float16*)(ws + (11u << 20));          // 8 MB
    _Float16* xe   = (_Float16*)(ws + (19u << 20));          // 84 MB
    unsigned* vote = (unsigned*)(ws + (103u << 20));         // 16 u32
    unsigned* barg = vote + 16;                              // 1 u32
    unsigned* bar  = vote + 256;                             // 16 x 32-u32 (fallback)
    unsigned* fbar = vote + 1024;                            // 16 x 16 x 4-u32 (fast)

    convert_wh_frag<<<dim3(512),     dim3(256), 0, stream>>>(Wh, Wf);
    convert_wx_frag<<<dim3(64),      dim3(256), 0, stream>>>(Wx, Wxf);
    embed_gather_frag<<<dim3(10240), dim3(256), 0, stream>>>(inputs, emb, xe);
    hipMemsetAsync(hA, 0, (size_t)BATCH * UDIM * sizeof(_Float16), stream);
    hipMemsetAsync(vote, 0, 8192, stream);

    rnn_persist<<<dim3(256), dim3(1024), 0, stream>>>(hA, hB, xe, Wf, Wxf, b,
                                                      vote, barg, bar, fbar);

    // T=80 even -> final h in hA
    out_proj<<<dim3(1024), dim3(256), 0, stream>>>(hA, Wo, bo, out);
}